// Round 7
// baseline (676.913 us; speedup 1.0000x reference)
//
#include <hip/hip_runtime.h>
#include <cstddef>
#include <cstdint>

// Shapes fixed by reference setup_inputs():
#define T_LEN 2048
#define B_SZ  32
#define D_SZ  512
#define BD    (B_SZ * D_SZ)   // 16384

// ---------------------------------------------------------------------------
// GEMM: per output element, single sequential fmaf chain over k=0..511
// ascending, then + bias[e]. Chain order (k0 asc, kq asc, x/y/z/w asc)
// bit-exact vs ref (per-output chain is invariant to i/j loop structure).
//
// R7 changes vs R5/R6 (measured 470 us, VALUBusy 84%, VGPR 80):
//  - Inner loop restructured for READ-ONCE fragments: per kq load all 8
//    A-fragments into NAMED locals a0..a7, then stream B one fragment at a
//    time. VGPR 80 < 100-needed proved the compiler was re-reading
//    fragments from LDS (~1.5-2x LDS amplification). 16 ds_read_b128 per
//    kq per thread by construction.
//  - A layout now LINEAR (no quad swizzle): wave's A-reads touch 4 rows ->
//    2-way bank aliasing = free (m136); all A addresses become base+imm.
//    B keeps XOR quad swizzle p=q^((row>>1)&3) (16 rows -> 8-way if linear).
//  - Everything else unchanged: glds staging (no ds_write, no prefetch
//    regs), ONE barrier per 16-wide K-chunk, bijective XCD swizzle
//    (FETCH 272->85 MB proven).
// NOTE: SQ_LDS_BANK_CONFLICT ~3.3e7 here is a glds wide-write artifact
// (identical across layouts) — not a real read conflict.
// NOTE: plain __launch_bounds__(256). (256,4) clamped to 64 VGPR and
// spilled acc[8][8] (8.5x regression). Do not re-add.
// ---------------------------------------------------------------------------
#define BM   128
#define BN   128

typedef const __attribute__((address_space(1))) uint32_t* gas1_t;
typedef __attribute__((address_space(3))) uint32_t* las3_t;

__global__ __launch_bounds__(256) void gemm8x8_kernel(
    const float* __restrict__ A,     // [rows, 512]
    const float* __restrict__ W,     // [512, 512]
    const float* __restrict__ bias,  // [512]
    float* __restrict__ Y)           // [rows, 512]
{
#pragma clang fp contract(off)
  __shared__ float As[2][BM * 16];     // 8 KB per buf, linear, glds dest
  __shared__ float Bs[2][BN * 16];     // 8 KB per buf, linear, glds dest

  const int tid = threadIdx.x;
  const int tx  = tid & 15;          // n-lane: n = tx + 16*j
  const int ty  = tid >> 4;          // m-lane: m = ty + 16*i (0..15)
  const int cB  = (tx >> 1) & 3;     // B read-side quad XOR

  // Bijective XCD swizzle (n-fast).
  const int nwg  = (int)(gridDim.x * gridDim.y);
  const int orig = (int)(blockIdx.y * gridDim.x + blockIdx.x);
  const int q    = nwg >> 3, r = nwg & 7;
  const int xcd  = orig & 7, loc = orig >> 3;
  const int tix  = (xcd < r ? xcd * (q + 1) : r * (q + 1) + (xcd - r) * q) + loc;
  const int m0   = (tix >> 2) * BM;   // gridDim.y == 4 (D_SZ/BN)
  const int n0   = (tix & 3) * BN;

  // glds staging: wave w stages A segs {2w,2w+1} and B segs {2w,2w+1};
  // lane l lands at seg_base + l*16B. A is linear: lane fetches its own
  // quad. B: lane fetches logical quad (l&3)^((rloc>>1)&3) so the XOR'd
  // read sees logical k ascending.
  const int lane  = tid & 63;
  const int wid   = tid >> 6;                      // 0..3
  const int rloc  = lane >> 2;
  const int qA4   = ((lane & 3) << 2);
  const int qB4   = (((lane & 3) ^ ((rloc >> 1) & 3)) << 2);
  const int s0    = 2 * wid, s1 = 2 * wid + 1;
  const int oS0   = s0 * 256, oS1 = s1 * 256;      // LDS float offsets
  const float* gA0 = A + (size_t)(m0 + s0 * 16 + rloc) * D_SZ + qA4;
  const float* gA1 = A + (size_t)(m0 + s1 * 16 + rloc) * D_SZ + qA4;
  const float* gB0 = W + (size_t)(n0 + s0 * 16 + rloc) * D_SZ + qB4;
  const float* gB1 = W + (size_t)(n0 + s1 * 16 + rloc) * D_SZ + qB4;

#define STAGE(BUF, KOFF)                                                      \
  do {                                                                        \
    __builtin_amdgcn_global_load_lds((gas1_t)(const void*)(gA0 + (KOFF)),     \
                                     (las3_t)(void*)(&As[BUF][oS0]), 16, 0, 0);\
    __builtin_amdgcn_global_load_lds((gas1_t)(const void*)(gA1 + (KOFF)),     \
                                     (las3_t)(void*)(&As[BUF][oS1]), 16, 0, 0);\
    __builtin_amdgcn_global_load_lds((gas1_t)(const void*)(gB0 + (KOFF)),     \
                                     (las3_t)(void*)(&Bs[BUF][oS0]), 16, 0, 0);\
    __builtin_amdgcn_global_load_lds((gas1_t)(const void*)(gB1 + (KOFF)),     \
                                     (las3_t)(void*)(&Bs[BUF][oS1]), 16, 0, 0);\
  } while (0)

  float acc[8][8];
#pragma unroll
  for (int i = 0; i < 8; ++i)
#pragma unroll
    for (int j = 0; j < 8; ++j) acc[i][j] = 0.0f;

  STAGE(0, 0);
  __syncthreads();

#pragma unroll 1
  for (int kc = 0; kc < 32; ++kc) {
    const int cur = kc & 1;
    if (kc + 1 < 32) STAGE(cur ^ 1, (kc + 1) * 16);

    const float* asb = &As[cur][0] + ty * 16;      // per-thread A base
    const float* bsb = &Bs[cur][0] + tx * 16;      // per-thread B base
#pragma unroll
    for (int kq = 0; kq < 4; ++kq) {
      const int aq = kq << 2;                      // A linear: imm offsets
      const int bq = ((kq ^ cB) & 3) << 2;         // B: phys quad of logical kq
      // Load all 8 A-fragments once (named -> held in VGPRs).
      const float4 a0 = *(const float4*)&asb[0 * 256 + aq];
      const float4 a1 = *(const float4*)&asb[1 * 256 + aq];
      const float4 a2 = *(const float4*)&asb[2 * 256 + aq];
      const float4 a3 = *(const float4*)&asb[3 * 256 + aq];
      const float4 a4 = *(const float4*)&asb[4 * 256 + aq];
      const float4 a5 = *(const float4*)&asb[5 * 256 + aq];
      const float4 a6 = *(const float4*)&asb[6 * 256 + aq];
      const float4 a7 = *(const float4*)&asb[7 * 256 + aq];
      // Stream B one fragment at a time: each LDS value read exactly once.
#pragma unroll
      for (int j = 0; j < 8; ++j) {
        const float4 b = *(const float4*)&bsb[j * 256 + bq];
#define FMA4(I, AV)                                                           \
        acc[I][j] = fmaf(AV.x, b.x, acc[I][j]);                               \
        acc[I][j] = fmaf(AV.y, b.y, acc[I][j]);                               \
        acc[I][j] = fmaf(AV.z, b.z, acc[I][j]);                               \
        acc[I][j] = fmaf(AV.w, b.w, acc[I][j]);
        FMA4(0, a0) FMA4(1, a1) FMA4(2, a2) FMA4(3, a3)
        FMA4(4, a4) FMA4(5, a5) FMA4(6, a6) FMA4(7, a7)
#undef FMA4
      }
    }
    __syncthreads();   // drains vmcnt: next buf landed; cur reads complete.
  }
#undef STAGE

#pragma unroll
  for (int i = 0; i < 8; ++i) {
    const int m = m0 + ty + 16 * i;
#pragma unroll
    for (int j = 0; j < 8; ++j) {
      const int n = n0 + tx + 16 * j;
      Y[(size_t)m * D_SZ + n] = acc[i][j] + bias[n];
    }
  }
}

// ---------------------------------------------------------------------------
// Chunked LIF scan with warm-up, writing out directly.
// T split into CHK=16 chunks of CLEN=128. Per thread per direction: 64-step
// warm-up from v=0 over the neighbor chunk (residual influence 2^-64 << ulp;
// any spike hard-resets v to exact 0 -> bit-exact merge; proven absmax=0
// in R5/R6), then 128 real steps. Step math identical to verified scan.
// R7: ca/cb ping-pong INSIDE the existing 12-body macro-unrolled structure
// — each group's 32 loads issue BEFORE the previous group's dependent
// chain, hiding load latency under the ~384-cyc chain. (R6 measured 3.1
// TB/s = half of achievable: the shared creg serialized load->chain->load.)
// R5 lesson still honored: body count unchanged, no CLEN=256 mega-unroll.
// ---------------------------------------------------------------------------
#define CHK  16
#define CLEN 128

__global__ __launch_bounds__(64) void scan_chunk_kernel(
    const float* __restrict__ Y,
    float* __restrict__ out)
{
#pragma clang fp contract(off)
  const int idx = blockIdx.x * 64 + threadIdx.x;   // column in [0, BD)
  const int c   = blockIdx.y;                      // chunk
  const int t0  = c * CLEN;
  float ca[32], cb[32];
  uint32_t sf0, sf1, sf2, sf3, sb0, sb1, sb2, sb3;
  float v;

#define LD(R, TB)                                                             \
  _Pragma("unroll")                                                           \
  for (int j = 0; j < 32; ++j) R[j] = Y[(size_t)((TB) + j) * BD + idx];

  // chain forward over R, recording bits into W (W may be a dummy).
#define FCH(R, W)                                                             \
  {                                                                           \
    uint32_t w_ = 0;                                                          \
    _Pragma("unroll")                                                         \
    for (int j = 0; j < 32; ++j) {                                            \
      v = v + (R[j] - v) * 0.5f;                                              \
      const bool s = (v - 1.0f) >= 0.0f;                                      \
      w_ |= (uint32_t)s << j;                                                 \
      v = s ? 0.0f : v;                                                       \
    }                                                                         \
    W = w_;                                                                   \
  }

#define BCH(R, W)                                                             \
  {                                                                           \
    uint32_t w_ = 0;                                                          \
    _Pragma("unroll")                                                         \
    for (int j = 31; j >= 0; --j) {                                           \
      v = v + (R[j] - v) * 0.5f;                                              \
      const bool s = (v - 1.0f) >= 0.0f;                                      \
      w_ |= (uint32_t)s << j;                                                 \
      v = s ? 0.0f : v;                                                       \
    }                                                                         \
    W = w_;                                                                   \
  }

  uint32_t wdump;   // warm-up bit sink (dead)

  // ---------------- forward (t ascending) ----------------
  v = 0.0f;
  if (c > 0) {                       // warm-up: 64 steps over tail of prev
    LD(ca, t0 - 64)
    LD(cb, t0 - 32)
    FCH(ca, wdump)
    LD(ca, t0)                       // real group 0 loads fly under cb chain
    FCH(cb, wdump)
  } else {
    LD(ca, t0)
  }
  LD(cb, t0 + 32)  FCH(ca, sf0)
  LD(ca, t0 + 64)  FCH(cb, sf1)
  LD(cb, t0 + 96)  FCH(ca, sf2)
                   FCH(cb, sf3)

  // ---------------- backward (t descending) ----------------
  v = 0.0f;
  if (c < CHK - 1) {                 // warm-up: 64 steps over head of next
    LD(ca, t0 + CLEN + 32)
    LD(cb, t0 + CLEN)
    BCH(ca, wdump)
    LD(ca, t0 + 96)                  // real group 3 loads fly under cb chain
    BCH(cb, wdump)
  } else {
    LD(ca, t0 + 96)
  }
  LD(cb, t0 + 64)  BCH(ca, sb3)
  LD(ca, t0 + 32)  BCH(cb, sb2)
  LD(cb, t0)       BCH(ca, sb1)
                   BCH(cb, sb0)

  // ---------------- write ----------------
#define WGRP(SF, SB, G)                                                       \
  _Pragma("unroll")                                                           \
  for (int j = 0; j < 32; ++j)                                                \
    out[(size_t)(t0 + (G) * 32 + j) * BD + idx] =                             \
        (float)(((SF >> j) & 1u) + ((SB >> j) & 1u));
  WGRP(sf0, sb0, 0) WGRP(sf1, sb1, 1) WGRP(sf2, sb2, 2) WGRP(sf3, sb3, 3)

#undef LD
#undef FCH
#undef BCH
#undef WGRP
}

// ---------------------------------------------------------------------------
// Fallback scans (used only if ws is too small for full Y).
// ---------------------------------------------------------------------------
__global__ __launch_bounds__(64) void lif_fwd_kernel(
    const float* __restrict__ Y, float* __restrict__ out,
    int tlen, float* __restrict__ vstate, int carry)
{
#pragma clang fp contract(off)
  const int idx = blockIdx.x * 64 + threadIdx.x;
  float v = carry ? vstate[idx] : 0.0f;
#pragma unroll 16
  for (int t = 0; t < tlen; ++t) {
    const float c = Y[(size_t)t * BD + idx];
    v = v + (c - v) * 0.5f;
    const bool s = (v - 1.0f) >= 0.0f;
    out[(size_t)t * BD + idx] = s ? 1.0f : 0.0f;
    v = s ? 0.0f : v;
  }
  vstate[idx] = v;
}

__global__ __launch_bounds__(64) void lif_bwd_kernel(
    const float* __restrict__ Y, float* __restrict__ out,
    int tlen, float* __restrict__ vstate, int carry)
{
#pragma clang fp contract(off)
  const int idx = blockIdx.x * 64 + threadIdx.x;
  float v = carry ? vstate[idx] : 0.0f;
#pragma unroll 16
  for (int tt = 0; tt < tlen; ++tt) {
    const size_t t = (size_t)(tlen - 1 - tt);
    const float c = Y[t * BD + idx];
    v = v + (c - v) * 0.5f;
    const bool s = (v - 1.0f) >= 0.0f;
    out[t * BD + idx] += s ? 1.0f : 0.0f;
    v = s ? 0.0f : v;
  }
  vstate[idx] = v;
}

// ---------------------------------------------------------------------------
extern "C" void kernel_launch(void* const* d_in, const int* in_sizes, int n_in,
                              void* d_out, int out_size, void* d_ws, size_t ws_size,
                              hipStream_t stream)
{
  const float* x = (const float*)d_in[0];   // [T, B, D]
  const float* W = (const float*)d_in[1];   // [D, D]
  const float* b = (const float*)d_in[2];   // [D]
  float* out = (float*)d_out;               // [T, B, D]

  const size_t full_bytes = (size_t)T_LEN * BD * sizeof(float);     // 134 MB
  const size_t vbytes     = (size_t)BD * sizeof(float);

  if (ws_size >= full_bytes) {
    float* Y = (float*)d_ws;
    dim3 grid(T_LEN * B_SZ / BM, D_SZ / BN);
    gemm8x8_kernel<<<grid, 256, 0, stream>>>(x, W, b, Y);
    scan_chunk_kernel<<<dim3(BD / 64, CHK), 64, 0, stream>>>(Y, out);
  } else {
    // Chunked fallback; Tc a power-of-two divisor of T_LEN (>=4) so chunk
    // rows are a multiple of BM=128.
    const size_t avail = ws_size > vbytes ? ws_size - vbytes : 0;
    int Tc = T_LEN;
    while (Tc > 4 && (size_t)Tc * BD * sizeof(float) > avail) Tc >>= 1;
    float* Y      = (float*)d_ws;
    float* vstate = (float*)((char*)d_ws + (size_t)Tc * BD * sizeof(float));

    int first = 1;
    for (int t0 = 0; t0 < T_LEN; t0 += Tc) {
      dim3 grid(Tc * B_SZ / BM, D_SZ / BN);
      gemm8x8_kernel<<<grid, 256, 0, stream>>>(x + (size_t)t0 * BD, W, b, Y);
      lif_fwd_kernel<<<BD / 64, 64, 0, stream>>>(Y, out + (size_t)t0 * BD, Tc,
                                                 vstate, first ? 0 : 1);
      first = 0;
    }
    first = 1;
    for (int t0 = T_LEN - Tc; t0 >= 0; t0 -= Tc) {
      dim3 grid(Tc * B_SZ / BM, D_SZ / BN);
      gemm8x8_kernel<<<grid, 256, 0, stream>>>(x + (size_t)t0 * BD, W, b, Y);
      lif_bwd_kernel<<<BD / 64, 64, 0, stream>>>(Y, out + (size_t)t0 * BD, Tc,
                                                 vstate, first ? 0 : 1);
      first = 0;
    }
  }
}